// Round 4
// baseline (518.010 us; speedup 1.0000x reference)
//
#include <hip/hip_runtime.h>

// Chamfer distance, fp32 VALU, register-tiled, packed-fp32 math.
// dist(p,q) = |p|^2 + |q|^2 - 2 p.q ; |p|^2 folded out of the min, |q|^2
// precomputed during LDS staging.
//
// R4: v_pk_fma_f32 packed pairs + 512-thread blocks -> 48.5us dispatch.
// R5: TSPLIT=2 (1024 blocks); launch_bounds(512,8) spill collapse, 53.5us.
// R6: bounds (512,4): spill gone, 50us, occupancy 33% -- TLP not the lever.
// R7: register software-pipeline of the j-loop: 46.3us (+8%, predicted
// +35%). lgkmcnt per j-step was not the dominant stall.
// R8 theory: VALU floor ~24us, duty 52%. Remaining structural stall is the
// staging phase: compute drains at a barrier, then 12 scalar global loads
// (~300-500cy L2 latency) sit exposed before the second barrier; all ~4
// resident blocks run the same period so their staging windows phase-lock
// (convoys) and nothing covers the hole. Fix: LDS double-buffer (TILE
// 64->32, 2 buffers in the same 33.8KB), T14 split: issue tile k+1 loads
// BEFORE compute of tile k, ds_write after, ONE barrier per tile. Predict:
// VALUBusy 63->80+, dispatch 46.3 -> 32-37us.

#define THREADS 512
#define P 8        // src points per thread (4 packed pairs)
#define S 32       // target slices per block (one 16-lane group per slice)
#define G 128      // src points per block = 16 lanes * P
#define TILE 32    // targets per slice per staging tile (double-buffered)
#define LSTRIDE (TILE + 1)  // +1 float4 pad -> disjoint banks across groups
#define TSPLIT 2   // target-dimension split across blocks
#define BUFSZ (S * LSTRIDE)

typedef float float2_t __attribute__((ext_vector_type(2)));
typedef float float4_t __attribute__((ext_vector_type(4)));

// d = a * bcast_lo(b) + bcast_hi(b)   (b = {qz,qw}: d = a*qz + qw)
static __device__ __forceinline__ float2_t pk_fma_bl_bh(float2_t a, float2_t b) {
  float2_t d;
  asm("v_pk_fma_f32 %0, %1, %2, %2 op_sel:[0,0,1] op_sel_hi:[1,0,1]"
      : "=v"(d) : "v"(a), "v"(b));
  return d;
}
// d = a * bcast_hi(b) + c
static __device__ __forceinline__ float2_t pk_fma_bh(float2_t a, float2_t b, float2_t c) {
  float2_t d;
  asm("v_pk_fma_f32 %0, %1, %2, %3 op_sel:[0,1,0] op_sel_hi:[1,1,1]"
      : "=v"(d) : "v"(a), "v"(b), "v"(c));
  return d;
}
// d = a * bcast_lo(b) + c
static __device__ __forceinline__ float2_t pk_fma_bl(float2_t a, float2_t b, float2_t c) {
  float2_t d;
  asm("v_pk_fma_f32 %0, %1, %2, %3 op_sel:[0,0,0] op_sel_hi:[1,0,1]"
      : "=v"(d) : "v"(a), "v"(b), "v"(c));
  return d;
}

__global__ __launch_bounds__(THREADS, 4) void chamfer_min_kernel(
    const float* __restrict__ pred, const float* __restrict__ target,
    float* __restrict__ wsmin, int M) {
  const int blocksPerDir = M / G;  // 64
  int bid = blockIdx.x;
  int pblk = bid % blocksPerDir;
  int rest = bid / blocksPerDir;
  int ts = rest % TSPLIT;          // which target half
  int bd = rest / TSPLIT;
  int dir = bd & 1;
  int b = bd >> 1;
  const float* src = (dir ? target : pred) + (size_t)b * M * 3;
  const float* ref = (dir ? pred : target) + (size_t)b * M * 3;

  __shared__ float4_t lds[2 * BUFSZ];  // 33.8 KB double buffer; epilogue reuse

  int t = threadIdx.x;
  int g = t >> 4;  // slice 0..31 (uniform per 16-lane group)
  int l = t & 15;

  float2_t a2x[P / 2], a2y[P / 2], a2z[P / 2];
  int pbase = pblk * G;
#pragma unroll
  for (int i = 0; i < P / 2; ++i) {
    int p0 = pbase + l + 16 * (2 * i);
    int p1 = pbase + l + 16 * (2 * i + 1);
    float x0 = src[p0 * 3 + 0], y0 = src[p0 * 3 + 1], z0 = src[p0 * 3 + 2];
    float x1 = src[p1 * 3 + 0], y1 = src[p1 * 3 + 1], z1 = src[p1 * 3 + 2];
    a2x[i] = (float2_t){-2.f * x0, -2.f * x1};
    a2y[i] = (float2_t){-2.f * y0, -2.f * y1};
    a2z[i] = (float2_t){-2.f * z0, -2.f * z1};
  }
  float mlo[P / 2], mhi[P / 2];
#pragma unroll
  for (int i = 0; i < P / 2; ++i) { mlo[i] = 3.0e38f; mhi[i] = 3.0e38f; }

  const int spanLen = M / TSPLIT;      // 4096 targets for this block
  const int tbase = ts * spanLen;
  const int sliceLen = spanLen / S;    // 128
  const int ntiles = sliceLen / TILE;  // 4

  // Staging: each thread owns 2 consecutive entries (6 floats) per tile.
  const int sidx = 2 * t;
  const int ss = sidx >> 5;            // entry slice (TILE=32)
  const int sjj = sidx & (TILE - 1);   // jj, jj+1 stay in-slice (even)
  const int nb = tbase + ss * sliceLen + sjj;  // + k*TILE per tile
  float rx0, ry0, rz0, rx1, ry1, rz1;

  // prologue: stage tile 0
  {
    int n = nb;  // k = 0
    rx0 = ref[n * 3 + 0]; ry0 = ref[n * 3 + 1]; rz0 = ref[n * 3 + 2];
    rx1 = ref[n * 3 + 3]; ry1 = ref[n * 3 + 4]; rz1 = ref[n * 3 + 5];
    float4_t* dst = lds + ss * LSTRIDE + sjj;
    dst[0] = (float4_t){rx0, ry0, rz0, rx0 * rx0 + ry0 * ry0 + rz0 * rz0};
    dst[1] = (float4_t){rx1, ry1, rz1, rx1 * rx1 + ry1 * ry1 + rz1 * rz1};
  }
  __syncthreads();

  int cur = 0;
  for (int k = 0; k < ntiles; ++k) {
    // T14: issue next tile's global loads BEFORE compute (land under it)
    if (k + 1 < ntiles) {
      int n = nb + (k + 1) * TILE;
      rx0 = ref[n * 3 + 0]; ry0 = ref[n * 3 + 1]; rz0 = ref[n * 3 + 2];
      rx1 = ref[n * 3 + 3]; ry1 = ref[n * 3 + 4]; rz1 = ref[n * 3 + 5];
    }
    const float4_t* tp = lds + cur * BUFSZ + g * LSTRIDE;
    // Register pipeline: q for step j held in regs while step j+1 loads.
    float4_t qc0 = tp[0], qc1 = tp[1], qc2 = tp[2], qc3 = tp[3];
#pragma unroll
    for (int j = 0; j < TILE; j += 4) {
      float4_t qn0, qn1, qn2, qn3;
      if (j + 4 < TILE) {  // compile-time under full unroll
        qn0 = tp[j + 4]; qn1 = tp[j + 5]; qn2 = tp[j + 6]; qn3 = tp[j + 7];
      }
      float2_t q0xy = __builtin_shufflevector(qc0, qc0, 0, 1);
      float2_t q0zw = __builtin_shufflevector(qc0, qc0, 2, 3);
      float2_t q1xy = __builtin_shufflevector(qc1, qc1, 0, 1);
      float2_t q1zw = __builtin_shufflevector(qc1, qc1, 2, 3);
      float2_t q2xy = __builtin_shufflevector(qc2, qc2, 0, 1);
      float2_t q2zw = __builtin_shufflevector(qc2, qc2, 2, 3);
      float2_t q3xy = __builtin_shufflevector(qc3, qc3, 0, 1);
      float2_t q3zw = __builtin_shufflevector(qc3, qc3, 2, 3);
#pragma unroll
      for (int i = 0; i < P / 2; ++i) {
        // d = ax*qx + ay*qy + az*qz + qw, two points per packed chain
        float2_t d0 = pk_fma_bl(a2x[i], q0xy,
                        pk_fma_bh(a2y[i], q0xy, pk_fma_bl_bh(a2z[i], q0zw)));
        float2_t d1 = pk_fma_bl(a2x[i], q1xy,
                        pk_fma_bh(a2y[i], q1xy, pk_fma_bl_bh(a2z[i], q1zw)));
        float2_t d2 = pk_fma_bl(a2x[i], q2xy,
                        pk_fma_bh(a2y[i], q2xy, pk_fma_bl_bh(a2z[i], q2zw)));
        float2_t d3 = pk_fma_bl(a2x[i], q3xy,
                        pk_fma_bh(a2y[i], q3xy, pk_fma_bl_bh(a2z[i], q3zw)));
        mlo[i] = fminf(fminf(mlo[i], d0.x), d1.x);  // v_min3
        mlo[i] = fminf(fminf(mlo[i], d2.x), d3.x);
        mhi[i] = fminf(fminf(mhi[i], d0.y), d1.y);
        mhi[i] = fminf(fminf(mhi[i], d2.y), d3.y);
      }
      if (j + 4 < TILE) { qc0 = qn0; qc1 = qn1; qc2 = qn2; qc3 = qn3; }
    }
    // write staged tile into the other buffer; one barrier per tile
    if (k + 1 < ntiles) {
      float4_t* dst = lds + (cur ^ 1) * BUFSZ + ss * LSTRIDE + sjj;
      dst[0] = (float4_t){rx0, ry0, rz0, rx0 * rx0 + ry0 * ry0 + rz0 * rz0};
      dst[1] = (float4_t){rx1, ry1, rz1, rx1 * rx1 + ry1 * ry1 + rz1 * rz1};
    }
    __syncthreads();
    cur ^= 1;
  }

  // Combine the S slice-mins per point, add |p|^2 back, store per-split min.
  float* lmin = (float*)lds;  // [S][G] floats (16 KB, overlays staging)
#pragma unroll
  for (int i = 0; i < P / 2; ++i) {
    lmin[g * G + (l + 16 * (2 * i))] = mlo[i];
    lmin[g * G + (l + 16 * (2 * i + 1))] = mhi[i];
  }
  __syncthreads();
  if (t < G) {
    float mn = 3.0e38f;
#pragma unroll
    for (int s = 0; s < S; ++s) mn = fminf(mn, lmin[s * G + t]);
    int p = pbase + t;
    float x = src[p * 3 + 0], y = src[p * 3 + 1], z = src[p * 3 + 2];
    int pid = (b * 2 + dir) * M + p;               // global point id
    wsmin[(size_t)pid * TSPLIT + ts] = (x * x + y * y + z * z) + mn;
  }
}

// Min over the TSPLIT partials per point, then sum everything (double acc).
__global__ __launch_bounds__(256) void chamfer_reduce_kernel(
    const float* __restrict__ wsmin, float* __restrict__ out, int npts,
    float scale) {
  int tid = blockIdx.x * blockDim.x + threadIdx.x;
  int stride = gridDim.x * blockDim.x;
  double acc = 0.0;
  for (int p = tid; p < npts; p += stride) {
    float2_t v = ((const float2_t*)wsmin)[p];  // TSPLIT=2 contiguous
    acc += (double)fminf(v.x, v.y);
  }
  for (int off = 32; off > 0; off >>= 1) acc += __shfl_down(acc, off, 64);
  __shared__ double wsum[256 / 64];
  int t = threadIdx.x;
  if ((t & 63) == 0) wsum[t >> 6] = acc;
  __syncthreads();
  if (t == 0) {
    double s = 0.0;
#pragma unroll
    for (int w = 0; w < 256 / 64; ++w) s += wsum[w];
    atomicAdd(out, (float)(s * (double)scale));
  }
}

extern "C" void kernel_launch(void* const* d_in, const int* in_sizes, int n_in,
                              void* d_out, int out_size, void* d_ws,
                              size_t ws_size, hipStream_t stream) {
  const float* pred = (const float*)d_in[0];
  const float* target = (const float*)d_in[1];
  float* out = (float*)d_out;
  float* wsmin = (float*)d_ws;  // B*2*M*TSPLIT floats = 512 KB
  const int B = 4;
  const int M = in_sizes[0] / (B * 3);  // 8192

  // mean_b[ mean_m(min) + mean_n(min) ] with M==N  ->  sum_all / (B*M)
  float scale = 1.0f / (float)(B * M);

  hipMemsetAsync(out, 0, sizeof(float), stream);  // d_out is poisoned 0xAA
  int blocks = B * 2 * (M / G) * TSPLIT;          // 1024
  chamfer_min_kernel<<<blocks, THREADS, 0, stream>>>(pred, target, wsmin, M);
  int npts = B * 2 * M;                           // 65536
  chamfer_reduce_kernel<<<64, 256, 0, stream>>>(wsmin, out, npts, scale);
}

// Round 5
// 176.939 us; speedup vs baseline: 2.9276x; 2.9276x over previous
//
#include <hip/hip_runtime.h>

// Chamfer distance, fp32 VALU, register-tiled, packed-fp32 math.
// dist(p,q) = |p|^2 + |q|^2 - 2 p.q ; |p|^2 folded out of the min, |q|^2
// precomputed during LDS staging.
//
// R4: v_pk_fma_f32 packed pairs + 512-thread blocks -> 48.5us dispatch.
// R5: TSPLIT=2 (1024 blocks); launch_bounds(512,8) spill collapse, 53.5us.
// R6: bounds (512,4): spill gone, 50us, occupancy 33% -- TLP not the lever.
// R7: register software-pipeline of the j-loop: 46.3us (+8%).
// R8: LDS double-buffer (TILE 32) + T14 early-issue staging regs ->
// 550us: allocator pinned VGPR=64 and spilled 1.5GB to scratch.
// POST-MORTEM: empirically arg2 of __launch_bounds__ acts as min BLOCKS/CU
// here: (512,8)->cap 32 (R5), (512,4)->cap 64 (R8). R8's structure needs
// ~80 VGPR; it was measured through a spill catastrophe, not on merit.
// R9: identical structure, bounds (512,2) -> cap 128. LDS still limits
// residency (33.8KB). Predict: VGPR 72-96, WRITE back to ~512B, and a
// clean test of the staging/convoy theory: dur 32-40us if right, ~46 if
// staging was already hidden.

#define THREADS 512
#define P 8        // src points per thread (4 packed pairs)
#define S 32       // target slices per block (one 16-lane group per slice)
#define G 128      // src points per block = 16 lanes * P
#define TILE 32    // targets per slice per staging tile (double-buffered)
#define LSTRIDE (TILE + 1)  // +1 float4 pad -> disjoint banks across groups
#define TSPLIT 2   // target-dimension split across blocks
#define BUFSZ (S * LSTRIDE)

typedef float float2_t __attribute__((ext_vector_type(2)));
typedef float float4_t __attribute__((ext_vector_type(4)));

// d = a * bcast_lo(b) + bcast_hi(b)   (b = {qz,qw}: d = a*qz + qw)
static __device__ __forceinline__ float2_t pk_fma_bl_bh(float2_t a, float2_t b) {
  float2_t d;
  asm("v_pk_fma_f32 %0, %1, %2, %2 op_sel:[0,0,1] op_sel_hi:[1,0,1]"
      : "=v"(d) : "v"(a), "v"(b));
  return d;
}
// d = a * bcast_hi(b) + c
static __device__ __forceinline__ float2_t pk_fma_bh(float2_t a, float2_t b, float2_t c) {
  float2_t d;
  asm("v_pk_fma_f32 %0, %1, %2, %3 op_sel:[0,1,0] op_sel_hi:[1,1,1]"
      : "=v"(d) : "v"(a), "v"(b), "v"(c));
  return d;
}
// d = a * bcast_lo(b) + c
static __device__ __forceinline__ float2_t pk_fma_bl(float2_t a, float2_t b, float2_t c) {
  float2_t d;
  asm("v_pk_fma_f32 %0, %1, %2, %3 op_sel:[0,0,0] op_sel_hi:[1,0,1]"
      : "=v"(d) : "v"(a), "v"(b), "v"(c));
  return d;
}

__global__ __launch_bounds__(THREADS, 2) void chamfer_min_kernel(
    const float* __restrict__ pred, const float* __restrict__ target,
    float* __restrict__ wsmin, int M) {
  const int blocksPerDir = M / G;  // 64
  int bid = blockIdx.x;
  int pblk = bid % blocksPerDir;
  int rest = bid / blocksPerDir;
  int ts = rest % TSPLIT;          // which target half
  int bd = rest / TSPLIT;
  int dir = bd & 1;
  int b = bd >> 1;
  const float* src = (dir ? target : pred) + (size_t)b * M * 3;
  const float* ref = (dir ? pred : target) + (size_t)b * M * 3;

  __shared__ float4_t lds[2 * BUFSZ];  // 33.8 KB double buffer; epilogue reuse

  int t = threadIdx.x;
  int g = t >> 4;  // slice 0..31 (uniform per 16-lane group)
  int l = t & 15;

  float2_t a2x[P / 2], a2y[P / 2], a2z[P / 2];
  int pbase = pblk * G;
#pragma unroll
  for (int i = 0; i < P / 2; ++i) {
    int p0 = pbase + l + 16 * (2 * i);
    int p1 = pbase + l + 16 * (2 * i + 1);
    float x0 = src[p0 * 3 + 0], y0 = src[p0 * 3 + 1], z0 = src[p0 * 3 + 2];
    float x1 = src[p1 * 3 + 0], y1 = src[p1 * 3 + 1], z1 = src[p1 * 3 + 2];
    a2x[i] = (float2_t){-2.f * x0, -2.f * x1};
    a2y[i] = (float2_t){-2.f * y0, -2.f * y1};
    a2z[i] = (float2_t){-2.f * z0, -2.f * z1};
  }
  float mlo[P / 2], mhi[P / 2];
#pragma unroll
  for (int i = 0; i < P / 2; ++i) { mlo[i] = 3.0e38f; mhi[i] = 3.0e38f; }

  const int spanLen = M / TSPLIT;      // 4096 targets for this block
  const int tbase = ts * spanLen;
  const int sliceLen = spanLen / S;    // 128
  const int ntiles = sliceLen / TILE;  // 4

  // Staging: each thread owns 2 consecutive entries (6 floats) per tile.
  const int sidx = 2 * t;
  const int ss = sidx >> 5;            // entry slice (TILE=32)
  const int sjj = sidx & (TILE - 1);   // jj, jj+1 stay in-slice (even)
  const int nb = tbase + ss * sliceLen + sjj;  // + k*TILE per tile
  float rx0, ry0, rz0, rx1, ry1, rz1;

  // prologue: stage tile 0
  {
    int n = nb;  // k = 0
    rx0 = ref[n * 3 + 0]; ry0 = ref[n * 3 + 1]; rz0 = ref[n * 3 + 2];
    rx1 = ref[n * 3 + 3]; ry1 = ref[n * 3 + 4]; rz1 = ref[n * 3 + 5];
    float4_t* dst = lds + ss * LSTRIDE + sjj;
    dst[0] = (float4_t){rx0, ry0, rz0, rx0 * rx0 + ry0 * ry0 + rz0 * rz0};
    dst[1] = (float4_t){rx1, ry1, rz1, rx1 * rx1 + ry1 * ry1 + rz1 * rz1};
  }
  __syncthreads();

  int cur = 0;
  for (int k = 0; k < ntiles; ++k) {
    // T14: issue next tile's global loads BEFORE compute (land under it)
    if (k + 1 < ntiles) {
      int n = nb + (k + 1) * TILE;
      rx0 = ref[n * 3 + 0]; ry0 = ref[n * 3 + 1]; rz0 = ref[n * 3 + 2];
      rx1 = ref[n * 3 + 3]; ry1 = ref[n * 3 + 4]; rz1 = ref[n * 3 + 5];
    }
    const float4_t* tp = lds + cur * BUFSZ + g * LSTRIDE;
    // Register pipeline: q for step j held in regs while step j+1 loads.
    float4_t qc0 = tp[0], qc1 = tp[1], qc2 = tp[2], qc3 = tp[3];
#pragma unroll
    for (int j = 0; j < TILE; j += 4) {
      float4_t qn0, qn1, qn2, qn3;
      if (j + 4 < TILE) {  // compile-time under full unroll
        qn0 = tp[j + 4]; qn1 = tp[j + 5]; qn2 = tp[j + 6]; qn3 = tp[j + 7];
      }
      float2_t q0xy = __builtin_shufflevector(qc0, qc0, 0, 1);
      float2_t q0zw = __builtin_shufflevector(qc0, qc0, 2, 3);
      float2_t q1xy = __builtin_shufflevector(qc1, qc1, 0, 1);
      float2_t q1zw = __builtin_shufflevector(qc1, qc1, 2, 3);
      float2_t q2xy = __builtin_shufflevector(qc2, qc2, 0, 1);
      float2_t q2zw = __builtin_shufflevector(qc2, qc2, 2, 3);
      float2_t q3xy = __builtin_shufflevector(qc3, qc3, 0, 1);
      float2_t q3zw = __builtin_shufflevector(qc3, qc3, 2, 3);
#pragma unroll
      for (int i = 0; i < P / 2; ++i) {
        // d = ax*qx + ay*qy + az*qz + qw, two points per packed chain
        float2_t d0 = pk_fma_bl(a2x[i], q0xy,
                        pk_fma_bh(a2y[i], q0xy, pk_fma_bl_bh(a2z[i], q0zw)));
        float2_t d1 = pk_fma_bl(a2x[i], q1xy,
                        pk_fma_bh(a2y[i], q1xy, pk_fma_bl_bh(a2z[i], q1zw)));
        float2_t d2 = pk_fma_bl(a2x[i], q2xy,
                        pk_fma_bh(a2y[i], q2xy, pk_fma_bl_bh(a2z[i], q2zw)));
        float2_t d3 = pk_fma_bl(a2x[i], q3xy,
                        pk_fma_bh(a2y[i], q3xy, pk_fma_bl_bh(a2z[i], q3zw)));
        mlo[i] = fminf(fminf(mlo[i], d0.x), d1.x);  // v_min3
        mlo[i] = fminf(fminf(mlo[i], d2.x), d3.x);
        mhi[i] = fminf(fminf(mhi[i], d0.y), d1.y);
        mhi[i] = fminf(fminf(mhi[i], d2.y), d3.y);
      }
      if (j + 4 < TILE) { qc0 = qn0; qc1 = qn1; qc2 = qn2; qc3 = qn3; }
    }
    // write staged tile into the other buffer; one barrier per tile
    if (k + 1 < ntiles) {
      float4_t* dst = lds + (cur ^ 1) * BUFSZ + ss * LSTRIDE + sjj;
      dst[0] = (float4_t){rx0, ry0, rz0, rx0 * rx0 + ry0 * ry0 + rz0 * rz0};
      dst[1] = (float4_t){rx1, ry1, rz1, rx1 * rx1 + ry1 * ry1 + rz1 * rz1};
    }
    __syncthreads();
    cur ^= 1;
  }

  // Combine the S slice-mins per point, add |p|^2 back, store per-split min.
  float* lmin = (float*)lds;  // [S][G] floats (16 KB, overlays staging)
#pragma unroll
  for (int i = 0; i < P / 2; ++i) {
    lmin[g * G + (l + 16 * (2 * i))] = mlo[i];
    lmin[g * G + (l + 16 * (2 * i + 1))] = mhi[i];
  }
  __syncthreads();
  if (t < G) {
    float mn = 3.0e38f;
#pragma unroll
    for (int s = 0; s < S; ++s) mn = fminf(mn, lmin[s * G + t]);
    int p = pbase + t;
    float x = src[p * 3 + 0], y = src[p * 3 + 1], z = src[p * 3 + 2];
    int pid = (b * 2 + dir) * M + p;               // global point id
    wsmin[(size_t)pid * TSPLIT + ts] = (x * x + y * y + z * z) + mn;
  }
}

// Min over the TSPLIT partials per point, then sum everything (double acc).
__global__ __launch_bounds__(256) void chamfer_reduce_kernel(
    const float* __restrict__ wsmin, float* __restrict__ out, int npts,
    float scale) {
  int tid = blockIdx.x * blockDim.x + threadIdx.x;
  int stride = gridDim.x * blockDim.x;
  double acc = 0.0;
  for (int p = tid; p < npts; p += stride) {
    float2_t v = ((const float2_t*)wsmin)[p];  // TSPLIT=2 contiguous
    acc += (double)fminf(v.x, v.y);
  }
  for (int off = 32; off > 0; off >>= 1) acc += __shfl_down(acc, off, 64);
  __shared__ double wsum[256 / 64];
  int t = threadIdx.x;
  if ((t & 63) == 0) wsum[t >> 6] = acc;
  __syncthreads();
  if (t == 0) {
    double s = 0.0;
#pragma unroll
    for (int w = 0; w < 256 / 64; ++w) s += wsum[w];
    atomicAdd(out, (float)(s * (double)scale));
  }
}

extern "C" void kernel_launch(void* const* d_in, const int* in_sizes, int n_in,
                              void* d_out, int out_size, void* d_ws,
                              size_t ws_size, hipStream_t stream) {
  const float* pred = (const float*)d_in[0];
  const float* target = (const float*)d_in[1];
  float* out = (float*)d_out;
  float* wsmin = (float*)d_ws;  // B*2*M*TSPLIT floats = 512 KB
  const int B = 4;
  const int M = in_sizes[0] / (B * 3);  // 8192

  // mean_b[ mean_m(min) + mean_n(min) ] with M==N  ->  sum_all / (B*M)
  float scale = 1.0f / (float)(B * M);

  hipMemsetAsync(out, 0, sizeof(float), stream);  // d_out is poisoned 0xAA
  int blocks = B * 2 * (M / G) * TSPLIT;          // 1024
  chamfer_min_kernel<<<blocks, THREADS, 0, stream>>>(pred, target, wsmin, M);
  int npts = B * 2 * M;                           // 65536
  chamfer_reduce_kernel<<<64, 256, 0, stream>>>(wsmin, out, npts, scale);
}

// Round 6
// 96.807 us; speedup vs baseline: 5.3510x; 1.8278x over previous
//
#include <hip/hip_runtime.h>

// Chamfer distance, fp32 VALU, register-tiled, packed-fp32 math.
// dist(p,q) = |p|^2 + |q|^2 - 2 p.q ; |p|^2 folded out of the min, |q|^2
// precomputed during LDS staging.
//
// R4: v_pk_fma_f32 packed pairs + 512-thread blocks -> 48.5us dispatch.
// R5-R6: TSPLIT=2; launch_bounds arg2 empirically = min BLOCKS/CU here
// ((512,8)->cap32, (512,4)->cap64). 50us clean at 44 VGPR.
// R7: manual register q-pipeline: 46.3us, 44 VGPR.
// R8: + dbuf/T14 at cap 64 -> spill catastrophe (550us).
// R9: same at cap 128 -> used ALL 128 and still spilled (130us). The
// fully-unrolled j-loop + named qn pipeline invites the compiler to hoist
// many steps' ds_reads -> live q-state ~8x16 regs. The manual pipeline IS
// the VGPR bomb (Common-mistake #5).
// R10: keep dbuf + T14 early-issue + one-barrier-per-tile (the untested
// staging/convoy fix); drop the manual q-pipeline (direct tp[j..j+3],
// unroll 2, as in R6). Predict VGPR 56-80, no spill; dur 33-38us if the
// staging theory is right, ~46us if staging was already hidden.

#define THREADS 512
#define P 8        // src points per thread (4 packed pairs)
#define S 32       // target slices per block (one 16-lane group per slice)
#define G 128      // src points per block = 16 lanes * P
#define TILE 32    // targets per slice per staging tile (double-buffered)
#define LSTRIDE (TILE + 1)  // +1 float4 pad -> disjoint banks across groups
#define TSPLIT 2   // target-dimension split across blocks
#define BUFSZ (S * LSTRIDE)

typedef float float2_t __attribute__((ext_vector_type(2)));
typedef float float4_t __attribute__((ext_vector_type(4)));

// d = a * bcast_lo(b) + bcast_hi(b)   (b = {qz,qw}: d = a*qz + qw)
static __device__ __forceinline__ float2_t pk_fma_bl_bh(float2_t a, float2_t b) {
  float2_t d;
  asm("v_pk_fma_f32 %0, %1, %2, %2 op_sel:[0,0,1] op_sel_hi:[1,0,1]"
      : "=v"(d) : "v"(a), "v"(b));
  return d;
}
// d = a * bcast_hi(b) + c
static __device__ __forceinline__ float2_t pk_fma_bh(float2_t a, float2_t b, float2_t c) {
  float2_t d;
  asm("v_pk_fma_f32 %0, %1, %2, %3 op_sel:[0,1,0] op_sel_hi:[1,1,1]"
      : "=v"(d) : "v"(a), "v"(b), "v"(c));
  return d;
}
// d = a * bcast_lo(b) + c
static __device__ __forceinline__ float2_t pk_fma_bl(float2_t a, float2_t b, float2_t c) {
  float2_t d;
  asm("v_pk_fma_f32 %0, %1, %2, %3 op_sel:[0,0,0] op_sel_hi:[1,0,1]"
      : "=v"(d) : "v"(a), "v"(b), "v"(c));
  return d;
}

__global__ __launch_bounds__(THREADS, 2) void chamfer_min_kernel(
    const float* __restrict__ pred, const float* __restrict__ target,
    float* __restrict__ wsmin, int M) {
  const int blocksPerDir = M / G;  // 64
  int bid = blockIdx.x;
  int pblk = bid % blocksPerDir;
  int rest = bid / blocksPerDir;
  int ts = rest % TSPLIT;          // which target half
  int bd = rest / TSPLIT;
  int dir = bd & 1;
  int b = bd >> 1;
  const float* src = (dir ? target : pred) + (size_t)b * M * 3;
  const float* ref = (dir ? pred : target) + (size_t)b * M * 3;

  __shared__ float4_t lds[2 * BUFSZ];  // 33.8 KB double buffer; epilogue reuse

  int t = threadIdx.x;
  int g = t >> 4;  // slice 0..31 (uniform per 16-lane group)
  int l = t & 15;

  float2_t a2x[P / 2], a2y[P / 2], a2z[P / 2];
  int pbase = pblk * G;
#pragma unroll
  for (int i = 0; i < P / 2; ++i) {
    int p0 = pbase + l + 16 * (2 * i);
    int p1 = pbase + l + 16 * (2 * i + 1);
    float x0 = src[p0 * 3 + 0], y0 = src[p0 * 3 + 1], z0 = src[p0 * 3 + 2];
    float x1 = src[p1 * 3 + 0], y1 = src[p1 * 3 + 1], z1 = src[p1 * 3 + 2];
    a2x[i] = (float2_t){-2.f * x0, -2.f * x1};
    a2y[i] = (float2_t){-2.f * y0, -2.f * y1};
    a2z[i] = (float2_t){-2.f * z0, -2.f * z1};
  }
  float mlo[P / 2], mhi[P / 2];
#pragma unroll
  for (int i = 0; i < P / 2; ++i) { mlo[i] = 3.0e38f; mhi[i] = 3.0e38f; }

  const int spanLen = M / TSPLIT;      // 4096 targets for this block
  const int tbase = ts * spanLen;
  const int sliceLen = spanLen / S;    // 128
  const int ntiles = sliceLen / TILE;  // 4

  // Staging: each thread owns 2 consecutive entries (6 floats) per tile.
  const int sidx = 2 * t;
  const int ss = sidx >> 5;            // entry slice (TILE=32)
  const int sjj = sidx & (TILE - 1);   // jj, jj+1 stay in-slice (even)
  const int nb = tbase + ss * sliceLen + sjj;  // + k*TILE per tile
  float rx0, ry0, rz0, rx1, ry1, rz1;

  // prologue: stage tile 0
  {
    int n = nb;  // k = 0
    rx0 = ref[n * 3 + 0]; ry0 = ref[n * 3 + 1]; rz0 = ref[n * 3 + 2];
    rx1 = ref[n * 3 + 3]; ry1 = ref[n * 3 + 4]; rz1 = ref[n * 3 + 5];
    float4_t* dst = lds + ss * LSTRIDE + sjj;
    dst[0] = (float4_t){rx0, ry0, rz0, rx0 * rx0 + ry0 * ry0 + rz0 * rz0};
    dst[1] = (float4_t){rx1, ry1, rz1, rx1 * rx1 + ry1 * ry1 + rz1 * rz1};
  }
  __syncthreads();

  int cur = 0;
  for (int k = 0; k < ntiles; ++k) {
    // T14: issue next tile's global loads BEFORE compute (land under it)
    if (k + 1 < ntiles) {
      int n = nb + (k + 1) * TILE;
      rx0 = ref[n * 3 + 0]; ry0 = ref[n * 3 + 1]; rz0 = ref[n * 3 + 2];
      rx1 = ref[n * 3 + 3]; ry1 = ref[n * 3 + 4]; rz1 = ref[n * 3 + 5];
    }
    const float4_t* tp = lds + cur * BUFSZ + g * LSTRIDE;
#pragma unroll 2
    for (int j = 0; j < TILE; j += 4) {
      float4_t q0 = tp[j + 0];  // broadcast reads, disjoint banks per wave
      float4_t q1 = tp[j + 1];
      float4_t q2 = tp[j + 2];
      float4_t q3 = tp[j + 3];
      float2_t q0xy = __builtin_shufflevector(q0, q0, 0, 1);
      float2_t q0zw = __builtin_shufflevector(q0, q0, 2, 3);
      float2_t q1xy = __builtin_shufflevector(q1, q1, 0, 1);
      float2_t q1zw = __builtin_shufflevector(q1, q1, 2, 3);
      float2_t q2xy = __builtin_shufflevector(q2, q2, 0, 1);
      float2_t q2zw = __builtin_shufflevector(q2, q2, 2, 3);
      float2_t q3xy = __builtin_shufflevector(q3, q3, 0, 1);
      float2_t q3zw = __builtin_shufflevector(q3, q3, 2, 3);
#pragma unroll
      for (int i = 0; i < P / 2; ++i) {
        // d = ax*qx + ay*qy + az*qz + qw, two points per packed chain
        float2_t d0 = pk_fma_bl(a2x[i], q0xy,
                        pk_fma_bh(a2y[i], q0xy, pk_fma_bl_bh(a2z[i], q0zw)));
        float2_t d1 = pk_fma_bl(a2x[i], q1xy,
                        pk_fma_bh(a2y[i], q1xy, pk_fma_bl_bh(a2z[i], q1zw)));
        float2_t d2 = pk_fma_bl(a2x[i], q2xy,
                        pk_fma_bh(a2y[i], q2xy, pk_fma_bl_bh(a2z[i], q2zw)));
        float2_t d3 = pk_fma_bl(a2x[i], q3xy,
                        pk_fma_bh(a2y[i], q3xy, pk_fma_bl_bh(a2z[i], q3zw)));
        mlo[i] = fminf(fminf(mlo[i], d0.x), d1.x);  // v_min3
        mlo[i] = fminf(fminf(mlo[i], d2.x), d3.x);
        mhi[i] = fminf(fminf(mhi[i], d0.y), d1.y);
        mhi[i] = fminf(fminf(mhi[i], d2.y), d3.y);
      }
    }
    // write staged tile into the other buffer; one barrier per tile
    if (k + 1 < ntiles) {
      float4_t* dst = lds + (cur ^ 1) * BUFSZ + ss * LSTRIDE + sjj;
      dst[0] = (float4_t){rx0, ry0, rz0, rx0 * rx0 + ry0 * ry0 + rz0 * rz0};
      dst[1] = (float4_t){rx1, ry1, rz1, rx1 * rx1 + ry1 * ry1 + rz1 * rz1};
    }
    __syncthreads();
    cur ^= 1;
  }

  // Combine the S slice-mins per point, add |p|^2 back, store per-split min.
  float* lmin = (float*)lds;  // [S][G] floats (16 KB, overlays staging)
#pragma unroll
  for (int i = 0; i < P / 2; ++i) {
    lmin[g * G + (l + 16 * (2 * i))] = mlo[i];
    lmin[g * G + (l + 16 * (2 * i + 1))] = mhi[i];
  }
  __syncthreads();
  if (t < G) {
    float mn = 3.0e38f;
#pragma unroll
    for (int s = 0; s < S; ++s) mn = fminf(mn, lmin[s * G + t]);
    int p = pbase + t;
    float x = src[p * 3 + 0], y = src[p * 3 + 1], z = src[p * 3 + 2];
    int pid = (b * 2 + dir) * M + p;               // global point id
    wsmin[(size_t)pid * TSPLIT + ts] = (x * x + y * y + z * z) + mn;
  }
}

// Min over the TSPLIT partials per point, then sum everything (double acc).
__global__ __launch_bounds__(256) void chamfer_reduce_kernel(
    const float* __restrict__ wsmin, float* __restrict__ out, int npts,
    float scale) {
  int tid = blockIdx.x * blockDim.x + threadIdx.x;
  int stride = gridDim.x * blockDim.x;
  double acc = 0.0;
  for (int p = tid; p < npts; p += stride) {
    float2_t v = ((const float2_t*)wsmin)[p];  // TSPLIT=2 contiguous
    acc += (double)fminf(v.x, v.y);
  }
  for (int off = 32; off > 0; off >>= 1) acc += __shfl_down(acc, off, 64);
  __shared__ double wsum[256 / 64];
  int t = threadIdx.x;
  if ((t & 63) == 0) wsum[t >> 6] = acc;
  __syncthreads();
  if (t == 0) {
    double s = 0.0;
#pragma unroll
    for (int w = 0; w < 256 / 64; ++w) s += wsum[w];
    atomicAdd(out, (float)(s * (double)scale));
  }
}

extern "C" void kernel_launch(void* const* d_in, const int* in_sizes, int n_in,
                              void* d_out, int out_size, void* d_ws,
                              size_t ws_size, hipStream_t stream) {
  const float* pred = (const float*)d_in[0];
  const float* target = (const float*)d_in[1];
  float* out = (float*)d_out;
  float* wsmin = (float*)d_ws;  // B*2*M*TSPLIT floats = 512 KB
  const int B = 4;
  const int M = in_sizes[0] / (B * 3);  // 8192

  // mean_b[ mean_m(min) + mean_n(min) ] with M==N  ->  sum_all / (B*M)
  float scale = 1.0f / (float)(B * M);

  hipMemsetAsync(out, 0, sizeof(float), stream);  // d_out is poisoned 0xAA
  int blocks = B * 2 * (M / G) * TSPLIT;          // 1024
  chamfer_min_kernel<<<blocks, THREADS, 0, stream>>>(pred, target, wsmin, M);
  int npts = B * 2 * M;                           // 65536
  chamfer_reduce_kernel<<<64, 256, 0, stream>>>(wsmin, out, npts, scale);
}